// Round 9
// baseline (672.019 us; speedup 1.0000x reference)
//
#include <hip/hip_runtime.h>

#define TSEQ 512
#define NTH  512    // 8 waves: 0-3 = role B (L0 matmul + ALL activations), 4-7 = role A (L1 matmul)
// 16 batch/block, 256 blocks = 1/CU. Two barriers per interval (mid + end).
// Pipeline: h0[t] (B,ph2,i=t) -> preact[t] (A,i=t+1) -> h1[t] (B,ph1,i=t+2).

typedef __attribute__((ext_vector_type(8))) short short8;
typedef __attribute__((ext_vector_type(4))) float f32x4;
typedef __attribute__((ext_vector_type(4))) unsigned int u32x4;

__device__ __forceinline__ unsigned rne16(float f) {
    unsigned u = __builtin_bit_cast(unsigned, f);
    return ((u + 0x7fffu + ((u >> 16) & 1u)) >> 16) & 0xffffu;
}
__device__ __forceinline__ void packPair(float a, float b, unsigned* hw, unsigned* lw) {
    unsigned ua = __builtin_bit_cast(unsigned, a), ub = __builtin_bit_cast(unsigned, b);
    unsigned ha = ua & 0xffff0000u, hb = ub & 0xffff0000u;
    *hw = (ha >> 16) | hb;
    *lw = rne16(a - __builtin_bit_cast(float, ha)) |
          (rne16(b - __builtin_bit_cast(float, hb)) << 16);
}
__device__ __forceinline__ void packA(const float w8[8], short8* fhi, short8* flo) {
    unsigned hw[8], lw[8];
    #pragma unroll
    for (int e = 0; e < 8; ++e) {
        unsigned u  = __builtin_bit_cast(unsigned, w8[e]);
        unsigned hb = u & 0xffff0000u;
        hw[e] = u >> 16;
        lw[e] = rne16(w8[e] - __builtin_bit_cast(float, hb));
    }
    u32x4 H = { hw[0] | (hw[1] << 16), hw[2] | (hw[3] << 16),
                hw[4] | (hw[5] << 16), hw[6] | (hw[7] << 16) };
    u32x4 L = { lw[0] | (lw[1] << 16), lw[2] | (lw[3] << 16),
                lw[4] | (lw[5] << 16), lw[6] | (lw[7] << 16) };
    *fhi = __builtin_bit_cast(short8, H);
    *flo = __builtin_bit_cast(short8, L);
}

#define MFMA(a, b, c) __builtin_amdgcn_mfma_f32_16x16x32_bf16((a), (b), (c), 0, 0, 0)
#define LD128(p) __builtin_bit_cast(short8, *(const u32x4*)(p))

// fused LSTM unit update: 5 exp2 + 3 rcp
__device__ __forceinline__ float act_fused(float ai, float af, float ag, float ao, float* c) {
    const float L2E = 1.44269504088896340736f;
    float ei = __builtin_amdgcn_exp2f(-ai * L2E);
    float ef = __builtin_amdgcn_exp2f(-af * L2E);
    float eg = __builtin_amdgcn_exp2f(2.0f * L2E * ag);
    float eo = __builtin_amdgcn_exp2f(-ao * L2E);
    float sf = __builtin_amdgcn_rcpf(1.0f + ef);
    float ig = (eg - 1.0f) * __builtin_amdgcn_rcpf((1.0f + ei) * (eg + 1.0f));
    float cn = fmaf(*c, sf, ig);
    *c = cn;
    float ec = __builtin_amdgcn_exp2f(2.0f * L2E * cn);
    return (ec - 1.0f) * __builtin_amdgcn_rcpf((1.0f + eo) * (ec + 1.0f));
}

__global__ __launch_bounds__(NTH, 2)
void lstm2_mfma(const float* __restrict__ x,
                const float* __restrict__ W_ih0, const float* __restrict__ W_hh0,
                const float* __restrict__ b_ih0, const float* __restrict__ b_hh0,
                const float* __restrict__ W_ih1, const float* __restrict__ W_hh1,
                const float* __restrict__ b_ih1, const float* __restrict__ b_hh1,
                const float* __restrict__ W_fc,  const float* __restrict__ b_fc,
                float* __restrict__ out)
{
    const int tid  = threadIdx.x;
    const int lane = tid & 63;
    const int wv   = tid >> 6;        // 0-3: role B, 4-7: role A
    const int rl   = lane & 15;       // MFMA row/col index = batch col n
    const int g    = lane >> 4;       // k-group 0..3
    const int b0   = blockIdx.x * 16;
    const int w    = wv & 3;          // row-tile id (units [16w,16w+16))

    // SINGLE-buffered planes: every producer->consumer edge crosses a barrier.
    __shared__ unsigned h0hi[512], h0lo[512], h1hi[512], h1lo[512];
    __shared__ f32x4 preact[4][4][64];   // [row-tile][gate][lane] raw L1 pre-acts
    __shared__ float fcl[64 * 17];

    for (int i2 = tid; i2 < 512; i2 += NTH) {
        h0hi[i2] = 0u; h0lo[i2] = 0u; h1hi[i2] = 0u; h1lo[i2] = 0u;
    }
    {
        float* pz = (float*)preact;
        for (int i2 = tid; i2 < 4096; i2 += NTH) pz[i2] = 0.f;
    }
    __syncthreads();

    // diagonal-swizzle b128 read offsets (loop-invariant)
    const int offL = rl*32 + (((g + rl) & 7) << 2);         // k-half 0
    const int offH = rl*32 + (((4 + g + rl) & 7) << 2);     // k-half 1
    const int q0w  = 8*w + 2*g;
    const int woff = rl*32 + ((((q0w >> 2) + rl) & 7) << 2) + (q0w & 3);

    if (wv < 4) {
        // ======== role B: L0 matmul + activations for BOTH layers ========
        short8 A0[4][2][2];   // [gate][k-half of W_hh0][hi/lo]
        short8 Ax[4];         // K-packed x-term
        f32x4  bias0[4];
        #pragma unroll
        for (int G = 0; G < 4; ++G) {
            const int row = 64*G + 16*w + rl;
            #pragma unroll
            for (int s = 0; s < 2; ++s) {
                float w8[8];
                const float* src = W_hh0 + row*64 + s*32 + g*8;
                #pragma unroll
                for (int e = 0; e < 8; ++e) w8[e] = src[e];
                packA(w8, &A0[G][s][0], &A0[G][s][1]);
            }
            {
                unsigned h01, l01, h23, l23;
                packPair(W_ih0[row*4+0], W_ih0[row*4+1], &h01, &l01);
                packPair(W_ih0[row*4+2], W_ih0[row*4+3], &h23, &l23);
                u32x4 ax;
                if (g == 0)      ax = (u32x4){h01, h23, h01, h23};
                else if (g == 1) ax = (u32x4){l01, l23, 0u, 0u};
                else             ax = (u32x4){0u, 0u, 0u, 0u};
                Ax[G] = __builtin_bit_cast(short8, ax);
            }
            const int rb = 64*G + 16*w + 4*g;
            bias0[G].x = b_ih0[rb+0] + b_hh0[rb+0];
            bias0[G].y = b_ih0[rb+1] + b_hh0[rb+1];
            bias0[G].z = b_ih0[rb+2] + b_hh0[rb+2];
            bias0[G].w = b_ih0[rb+3] + b_hh0[rb+3];
        }
        float c0[4] = {0.f,0.f,0.f,0.f}, c1[4] = {0.f,0.f,0.f,0.f};
        const int u0 = 16*w + 4*g;
        f32x4 xcur = *(const f32x4*)(x + ((size_t)(b0 + rl) * TSEQ) * 4);

        for (int i = 0; i <= TSEQ + 1; ++i) {
            const bool doL0 = (i < TSEQ);
            // ---------------- phase 1 ----------------
            // L1 pre-acts for step t=i-2 (zeros for i<2 -> c1 stays 0, h1=0: harmless)
            f32x4 pa0 = preact[w][0][lane];
            f32x4 pa1 = preact[w][1][lane];
            f32x4 pa2 = preact[w][2][lane];
            f32x4 pa3 = preact[w][3][lane];

            short8 Bh0, Bl0, Bh1, Bl1;
            f32x4 accL[4];
            if (doL0) {
                Bh0 = LD128(h0hi + offL);
                Bl0 = LD128(h0lo + offL);
                Bh1 = LD128(h0hi + offH);
                Bl1 = LD128(h0lo + offH);
                unsigned xh01, xl01, xh23, xl23;
                packPair(xcur.x, xcur.y, &xh01, &xl01);
                packPair(xcur.z, xcur.w, &xh23, &xl23);
                u32x4 tx = { (g < 2) ? xh01 : 0u, (g < 2) ? xh23 : 0u,
                             (g == 0) ? xl01 : 0u, (g == 0) ? xl23 : 0u };
                short8 Bx = __builtin_bit_cast(short8, tx);
                #pragma unroll
                for (int G = 0; G < 4; ++G) accL[G] = MFMA(Ax[G], Bx, bias0[G]);
            }

            // L1 activation (trans pipe; overlaps role-A's MFMA on this SIMD)
            float hv1[4];
            #pragma unroll
            for (int j = 0; j < 4; ++j)
                hv1[j] = act_fused(pa0[j], pa1[j], pa2[j], pa3[j], &c1[j]);
            {
                unsigned hw0, lw0, hw1, lw1;
                packPair(hv1[0], hv1[1], &hw0, &lw0);
                packPair(hv1[2], hv1[3], &hw1, &lw1);
                *(uint2*)(h1hi + woff) = make_uint2(hw0, hw1);
                *(uint2*)(h1lo + woff) = make_uint2(lw0, lw1);
            }
            if (i == TSEQ + 1) {   // hv1 = h1[511]
                #pragma unroll
                for (int j = 0; j < 4; ++j) fcl[(u0 + j)*17 + rl] = hv1[j];
            }

            if (doL0) {
                __builtin_amdgcn_s_setprio(1);
                #pragma unroll
                for (int G = 0; G < 4; ++G) accL[G] = MFMA(A0[G][0][0], Bh0, accL[G]);
                #pragma unroll
                for (int G = 0; G < 4; ++G) accL[G] = MFMA(A0[G][0][0], Bl0, accL[G]);
                #pragma unroll
                for (int G = 0; G < 4; ++G) accL[G] = MFMA(A0[G][0][1], Bh0, accL[G]);
                #pragma unroll
                for (int G = 0; G < 4; ++G) accL[G] = MFMA(A0[G][1][0], Bh1, accL[G]);
                #pragma unroll
                for (int G = 0; G < 4; ++G) accL[G] = MFMA(A0[G][1][0], Bl1, accL[G]);
                #pragma unroll
                for (int G = 0; G < 4; ++G) accL[G] = MFMA(A0[G][1][1], Bh1, accL[G]);
                __builtin_amdgcn_s_setprio(0);
            }
            __syncthreads();   // mid barrier
            // ---------------- phase 2 ----------------
            if (doL0) {
                float hv0[4];
                #pragma unroll
                for (int j = 0; j < 4; ++j)
                    hv0[j] = act_fused(accL[0][j], accL[1][j], accL[2][j], accL[3][j], &c0[j]);
                unsigned hw0, lw0, hw1, lw1;
                packPair(hv0[0], hv0[1], &hw0, &lw0);
                packPair(hv0[2], hv0[3], &hw1, &lw1);
                *(uint2*)(h0hi + woff) = make_uint2(hw0, hw1);
                *(uint2*)(h0lo + woff) = make_uint2(lw0, lw1);
                if (i + 1 < TSEQ)
                    xcur = *(const f32x4*)(x + ((size_t)(b0 + rl) * TSEQ + (i + 1)) * 4);
            }
            __syncthreads();   // end barrier
        }
    } else {
        // ======== role A: pure L1 matmul for step t=i-1; writes raw pre-acts ========
        short8 A1[4][4][2];   // s=0,1: W_ih1 (vs h0); s=2,3: W_hh1 (vs h1)
        f32x4  bias1[4];
        #pragma unroll
        for (int G = 0; G < 4; ++G) {
            const int row = 64*G + 16*w + rl;
            #pragma unroll
            for (int s = 0; s < 4; ++s) {
                float w8[8];
                const float* src = (s < 2) ? (W_ih1 + row*64 + s*32 + g*8)
                                           : (W_hh1 + row*64 + (s-2)*32 + g*8);
                #pragma unroll
                for (int e = 0; e < 8; ++e) w8[e] = src[e];
                packA(w8, &A1[G][s][0], &A1[G][s][1]);
            }
            const int rb = 64*G + 16*w + 4*g;
            bias1[G].x = b_ih1[rb+0] + b_hh1[rb+0];
            bias1[G].y = b_ih1[rb+1] + b_hh1[rb+1];
            bias1[G].z = b_ih1[rb+2] + b_hh1[rb+2];
            bias1[G].w = b_ih1[rb+3] + b_hh1[rb+3];
        }

        for (int i = 0; i <= TSEQ + 1; ++i) {
            const bool doA = (i >= 1);
            f32x4 acc[4];
            // ---------------- phase 1: s=0,1 on h0[i-1] ----------------
            if (doA) {
                short8 Bh0 = LD128(h0hi + offL);
                short8 Bl0 = LD128(h0lo + offL);
                short8 Bh1 = LD128(h0hi + offH);
                short8 Bl1 = LD128(h0lo + offH);
                __builtin_amdgcn_s_setprio(1);
                #pragma unroll
                for (int G = 0; G < 4; ++G) acc[G] = MFMA(A1[G][0][0], Bh0, bias1[G]);
                #pragma unroll
                for (int G = 0; G < 4; ++G) acc[G] = MFMA(A1[G][0][0], Bl0, acc[G]);
                #pragma unroll
                for (int G = 0; G < 4; ++G) acc[G] = MFMA(A1[G][0][1], Bh0, acc[G]);
                #pragma unroll
                for (int G = 0; G < 4; ++G) acc[G] = MFMA(A1[G][1][0], Bh1, acc[G]);
                #pragma unroll
                for (int G = 0; G < 4; ++G) acc[G] = MFMA(A1[G][1][0], Bl1, acc[G]);
                #pragma unroll
                for (int G = 0; G < 4; ++G) acc[G] = MFMA(A1[G][1][1], Bh1, acc[G]);
                __builtin_amdgcn_s_setprio(0);
            } else {
                #pragma unroll
                for (int G = 0; G < 4; ++G) acc[G] = (f32x4){0.f,0.f,0.f,0.f};
            }
            __syncthreads();   // mid barrier (h1[i-2] now written by role B)
            // ---------------- phase 2: s=2,3 on h1[i-2]; write pre-acts ----------------
            if (doA) {
                short8 Bh2 = LD128(h1hi + offL);
                short8 Bl2 = LD128(h1lo + offL);
                short8 Bh3 = LD128(h1hi + offH);
                short8 Bl3 = LD128(h1lo + offH);
                __builtin_amdgcn_s_setprio(1);
                #pragma unroll
                for (int G = 0; G < 4; ++G) acc[G] = MFMA(A1[G][2][0], Bh2, acc[G]);
                #pragma unroll
                for (int G = 0; G < 4; ++G) acc[G] = MFMA(A1[G][2][0], Bl2, acc[G]);
                #pragma unroll
                for (int G = 0; G < 4; ++G) acc[G] = MFMA(A1[G][2][1], Bh2, acc[G]);
                #pragma unroll
                for (int G = 0; G < 4; ++G) acc[G] = MFMA(A1[G][3][0], Bh3, acc[G]);
                #pragma unroll
                for (int G = 0; G < 4; ++G) acc[G] = MFMA(A1[G][3][0], Bl3, acc[G]);
                #pragma unroll
                for (int G = 0; G < 4; ++G) acc[G] = MFMA(A1[G][3][1], Bh3, acc[G]);
                __builtin_amdgcn_s_setprio(0);
            }
            preact[w][0][lane] = acc[0];
            preact[w][1][lane] = acc[1];
            preact[w][2][lane] = acc[2];
            preact[w][3][lane] = acc[3];
            __syncthreads();   // end barrier
        }
    }

    // ---- FC: out[b] = h1_last[b,:] . W_fc + b_fc ----
    if (tid < 16) {
        float acc = b_fc[0];
        #pragma unroll 16
        for (int u = 0; u < 64; ++u) acc += fcl[u*17 + tid] * W_fc[u];
        out[b0 + tid] = acc;
    }
}

extern "C" void kernel_launch(void* const* d_in, const int* in_sizes, int n_in,
                              void* d_out, int out_size, void* d_ws, size_t ws_size,
                              hipStream_t stream) {
    const float* x     = (const float*)d_in[0];
    const float* W_ih0 = (const float*)d_in[1];
    const float* W_hh0 = (const float*)d_in[2];
    const float* b_ih0 = (const float*)d_in[3];
    const float* b_hh0 = (const float*)d_in[4];
    const float* W_ih1 = (const float*)d_in[5];
    const float* W_hh1 = (const float*)d_in[6];
    const float* b_ih1 = (const float*)d_in[7];
    const float* b_hh1 = (const float*)d_in[8];
    const float* W_fc  = (const float*)d_in[9];
    const float* b_fc  = (const float*)d_in[10];
    float* out = (float*)d_out;

    dim3 grid(4096 / 16), block(NTH);
    hipLaunchKernelGGL(lstm2_mfma, grid, block, 0, stream,
                       x, W_ih0, W_hh0, b_ih0, b_hh0,
                       W_ih1, W_hh1, b_ih1, b_hh1, W_fc, b_fc, out);
}

// Round 10
// 472.682 us; speedup vs baseline: 1.4217x; 1.4217x over previous
//
#include <hip/hip_runtime.h>

#define TSEQ 512
#define NTH  512    // 8 waves: 0-3 layer0, 4-7 layer1 (skew 2); 16 batch/block, 256 blocks = 1/CU
// R10: h stored as SINGLE bf16-RNE plane (no lo residual); weights keep hi+lo split.
// MFMA/SIMD/step 76 -> 52. W*(h_bf16) errors are dynamic (decorrelate across t).

typedef __attribute__((ext_vector_type(8))) short short8;
typedef __attribute__((ext_vector_type(4))) float f32x4;
typedef __attribute__((ext_vector_type(4))) unsigned int u32x4;

__device__ __forceinline__ unsigned rne16(float f) {
    unsigned u = __builtin_bit_cast(unsigned, f);
    return ((u + 0x7fffu + ((u >> 16) & 1u)) >> 16) & 0xffffu;
}
// pack two f32 into one bf16-RNE pair word
__device__ __forceinline__ unsigned packRne2(float a, float b) {
    return rne16(a) | (rne16(b) << 16);
}
// pack two f32 into hi word (trunc pair) + lo word (rne residual pair) — for x only
__device__ __forceinline__ void packPair(float a, float b, unsigned* hw, unsigned* lw) {
    unsigned ua = __builtin_bit_cast(unsigned, a), ub = __builtin_bit_cast(unsigned, b);
    unsigned ha = ua & 0xffff0000u, hb = ub & 0xffff0000u;
    *hw = (ha >> 16) | hb;
    *lw = rne16(a - __builtin_bit_cast(float, ha)) |
          (rne16(b - __builtin_bit_cast(float, hb)) << 16);
}
// split 8 f32 weights into hi/lo bf16x8 A-fragments (element e <-> k-offset e)
__device__ __forceinline__ void packA(const float w8[8], short8* fhi, short8* flo) {
    unsigned hw[8], lw[8];
    #pragma unroll
    for (int e = 0; e < 8; ++e) {
        unsigned u  = __builtin_bit_cast(unsigned, w8[e]);
        unsigned hb = u & 0xffff0000u;
        hw[e] = u >> 16;
        lw[e] = rne16(w8[e] - __builtin_bit_cast(float, hb));
    }
    u32x4 H = { hw[0] | (hw[1] << 16), hw[2] | (hw[3] << 16),
                hw[4] | (hw[5] << 16), hw[6] | (hw[7] << 16) };
    u32x4 L = { lw[0] | (lw[1] << 16), lw[2] | (lw[3] << 16),
                lw[4] | (lw[5] << 16), lw[6] | (lw[7] << 16) };
    *fhi = __builtin_bit_cast(short8, H);
    *flo = __builtin_bit_cast(short8, L);
}

#define MFMA(a, b, c) __builtin_amdgcn_mfma_f32_16x16x32_bf16((a), (b), (c), 0, 0, 0)
#define LD128(p) __builtin_bit_cast(short8, *(const u32x4*)(p))

// fused LSTM unit update: 5 exp2 + 3 rcp
__device__ __forceinline__ float act_fused(float ai, float af, float ag, float ao, float* c) {
    const float L2E = 1.44269504088896340736f;
    float ei = __builtin_amdgcn_exp2f(-ai * L2E);
    float ef = __builtin_amdgcn_exp2f(-af * L2E);
    float eg = __builtin_amdgcn_exp2f(2.0f * L2E * ag);
    float eo = __builtin_amdgcn_exp2f(-ao * L2E);
    float sf = __builtin_amdgcn_rcpf(1.0f + ef);
    float ig = (eg - 1.0f) * __builtin_amdgcn_rcpf((1.0f + ei) * (eg + 1.0f));
    float cn = fmaf(*c, sf, ig);
    *c = cn;
    float ec = __builtin_amdgcn_exp2f(2.0f * L2E * cn);
    return (ec - 1.0f) * __builtin_amdgcn_rcpf((1.0f + eo) * (ec + 1.0f));
}

__global__ __launch_bounds__(NTH, 2)
void lstm2_mfma(const float* __restrict__ x,
                const float* __restrict__ W_ih0, const float* __restrict__ W_hh0,
                const float* __restrict__ b_ih0, const float* __restrict__ b_hh0,
                const float* __restrict__ W_ih1, const float* __restrict__ W_hh1,
                const float* __restrict__ b_ih1, const float* __restrict__ b_hh1,
                const float* __restrict__ W_fc,  const float* __restrict__ b_fc,
                float* __restrict__ out)
{
    const int tid  = threadIdx.x;
    const int lane = tid & 63;
    const int wv   = tid >> 6;        // 0-3: layer0, 4-7: layer1
    const int rl   = lane & 15;       // MFMA row/col index = batch col n
    const int g    = lane >> 4;       // k-group 0..3
    const int b0   = blockIdx.x * 16;

    // bf16-RNE h planes (2 units/word), depth-2 ping-pong, compile-time bases.
    // h[t] lives at parity (t+1)&1.
    __shared__ unsigned h0P0[512], h0P1[512];
    __shared__ unsigned h1P0[512], h1P1[512];
    __shared__ float fcl[64 * 17];    // padded 16->17

    for (int i2 = tid; i2 < 512; i2 += NTH) {
        h0P0[i2] = 0u; h0P1[i2] = 0u; h1P0[i2] = 0u; h1P1[i2] = 0u;
    }
    __syncthreads();

    // diagonal-swizzle b128 read offsets (loop-invariant)
    const int offL = rl*32 + (((g + rl) & 7) << 2);         // k-half 0
    const int offH = rl*32 + (((4 + g + rl) & 7) << 2);     // k-half 1
    const int q0w  = 8*((wv & 3)) + 2*g;
    const int woff = rl*32 + ((((q0w >> 2) + rl) & 7) << 2) + (q0w & 3);

    if (wv < 4) {
        // ======== LAYER 0: wave w owns u in [16w,16w+16) for all 4 gates ========
        const int w = wv;
        short8 A0[4][2][2];   // [gate][k-half of W_hh0][hi/lo]
        short8 Ax[4];         // K-packed x-term: k0-3 Whi(xhi), k4-7 Whi(xlo), k8-11 Wlo(xhi)
        f32x4  bias4[4];
        #pragma unroll
        for (int G = 0; G < 4; ++G) {
            const int row = 64*G + 16*w + rl;
            #pragma unroll
            for (int s = 0; s < 2; ++s) {
                float w8[8];
                const float* src = W_hh0 + row*64 + s*32 + g*8;
                #pragma unroll
                for (int e = 0; e < 8; ++e) w8[e] = src[e];
                packA(w8, &A0[G][s][0], &A0[G][s][1]);
            }
            {
                unsigned h01, l01, h23, l23;
                packPair(W_ih0[row*4+0], W_ih0[row*4+1], &h01, &l01);
                packPair(W_ih0[row*4+2], W_ih0[row*4+3], &h23, &l23);
                u32x4 ax;
                if (g == 0)      ax = (u32x4){h01, h23, h01, h23};   // k0-3: Whi, k4-7: Whi(dup)
                else if (g == 1) ax = (u32x4){l01, l23, 0u, 0u};     // k8-11: Wlo
                else             ax = (u32x4){0u, 0u, 0u, 0u};
                Ax[G] = __builtin_bit_cast(short8, ax);
            }
            const int rb = 64*G + 16*w + 4*g;
            bias4[G].x = b_ih0[rb+0] + b_hh0[rb+0];
            bias4[G].y = b_ih0[rb+1] + b_hh0[rb+1];
            bias4[G].z = b_ih0[rb+2] + b_hh0[rb+2];
            bias4[G].w = b_ih0[rb+3] + b_hh0[rb+3];
        }
        float cst[4] = {0.f, 0.f, 0.f, 0.f};

        // x[t] register-prefetched; every lane loads its batch col rl (L1/L2 broadcast)
        f32x4 xcur = *(const f32x4*)(x + ((size_t)(b0 + rl) * TSEQ) * 4);

        auto body0 = [&](const unsigned* rP, unsigned* wP, int i) {
            // h0[t-1] B-frags (bf16-RNE single plane)
            short8 B0 = LD128(rP + offL);
            short8 B1 = LD128(rP + offH);
            // x B-frag built in-lane from registers (k0-3 xhi, k4-7 xlo, k8-11 xhi)
            unsigned xh01, xl01, xh23, xl23;
            packPair(xcur.x, xcur.y, &xh01, &xl01);
            packPair(xcur.z, xcur.w, &xh23, &xl23);
            u32x4 tx = { (g < 2) ? xh01 : 0u, (g < 2) ? xh23 : 0u,
                         (g == 0) ? xl01 : 0u, (g == 0) ? xl23 : 0u };
            short8 Bx = __builtin_bit_cast(short8, tx);

            f32x4 acc[4];
            __builtin_amdgcn_s_setprio(1);
            // x-group first: register-only operands, no LDS wait
            #pragma unroll
            for (int G = 0; G < 4; ++G) acc[G] = MFMA(Ax[G], Bx, bias4[G]);
            #pragma unroll
            for (int G = 0; G < 4; ++G) acc[G] = MFMA(A0[G][0][0], B0, acc[G]);
            #pragma unroll
            for (int G = 0; G < 4; ++G) acc[G] = MFMA(A0[G][0][1], B0, acc[G]);
            #pragma unroll
            for (int G = 0; G < 4; ++G) acc[G] = MFMA(A0[G][1][0], B1, acc[G]);
            #pragma unroll
            for (int G = 0; G < 4; ++G) acc[G] = MFMA(A0[G][1][1], B1, acc[G]);
            __builtin_amdgcn_s_setprio(0);

            float hv[4];
            #pragma unroll
            for (int j = 0; j < 4; ++j)
                hv[j] = act_fused(acc[0][j], acc[1][j], acc[2][j], acc[3][j], &cst[j]);
            *(uint2*)(wP + woff) = make_uint2(packRne2(hv[0], hv[1]),
                                              packRne2(hv[2], hv[3]));

            if (i + 1 < TSEQ)
                xcur = *(const f32x4*)(x + ((size_t)(b0 + rl) * TSEQ + (i + 1)) * 4);
        };

        for (int ii = 0; ii < 256; ++ii) {
            body0(h0P0, h0P1, 2*ii);     __syncthreads();  // i=2ii   (p=0)
            body0(h0P1, h0P0, 2*ii + 1); __syncthreads();  // i=2ii+1 (p=1)
        }
        __syncthreads();   // i=512 slot (L1 tail)
        __syncthreads();   // i=513 slot (L1 tail)
    } else {
        // ======== LAYER 1 (skew 2): iter i computes t=i-2; h0 frags prefetched at i-1 ====
        const int w = wv - 4;
        short8 A1[4][4][2];   // s=0,1: W_ih1 (vs h0); s=2,3: W_hh1 (vs h1); [hi/lo]
        f32x4  bias4[4];
        #pragma unroll
        for (int G = 0; G < 4; ++G) {
            const int row = 64*G + 16*w + rl;
            #pragma unroll
            for (int s = 0; s < 4; ++s) {
                float w8[8];
                const float* src = (s < 2) ? (W_ih1 + row*64 + s*32 + g*8)
                                           : (W_hh1 + row*64 + (s-2)*32 + g*8);
                #pragma unroll
                for (int e = 0; e < 8; ++e) w8[e] = src[e];
                packA(w8, &A1[G][s][0], &A1[G][s][1]);
            }
            const int rb = 64*G + 16*w + 4*g;
            bias4[G].x = b_ih1[rb+0] + b_hh1[rb+0];
            bias4[G].y = b_ih1[rb+1] + b_hh1[rb+1];
            bias4[G].z = b_ih1[rb+2] + b_hh1[rb+2];
            bias4[G].w = b_ih1[rb+3] + b_hh1[rb+3];
        }
        float cst[4] = {0.f, 0.f, 0.f, 0.f};
        const int u0 = 16*w + 4*g;

        short8 pB0 = {}, pB1 = {};   // prefetched h0[t] frags

        auto body1 = [&](const unsigned* r1P,               // h1[t-1] read plane (p)
                         unsigned* wP,                      // h1[t] write plane (p^1)
                         const unsigned* n0P,               // h0 prefetch plane (p)
                         bool wrFC) {
            // h1 reads issue at top; consumed 4 MFMA-groups later (latency hidden)
            short8 B2 = LD128(r1P + offL);
            short8 B3 = LD128(r1P + offH);

            f32x4 acc[4];
            __builtin_amdgcn_s_setprio(1);
            // s=0,1 on prefetched h0 frags: start immediately after barrier
            #pragma unroll
            for (int G = 0; G < 4; ++G) acc[G] = MFMA(A1[G][0][0], pB0, bias4[G]);
            #pragma unroll
            for (int G = 0; G < 4; ++G) acc[G] = MFMA(A1[G][0][1], pB0, acc[G]);
            #pragma unroll
            for (int G = 0; G < 4; ++G) acc[G] = MFMA(A1[G][1][0], pB1, acc[G]);
            #pragma unroll
            for (int G = 0; G < 4; ++G) acc[G] = MFMA(A1[G][1][1], pB1, acc[G]);
            // s=2,3 on just-read h1 frags
            #pragma unroll
            for (int G = 0; G < 4; ++G) acc[G] = MFMA(A1[G][2][0], B2, acc[G]);
            #pragma unroll
            for (int G = 0; G < 4; ++G) acc[G] = MFMA(A1[G][2][1], B2, acc[G]);
            #pragma unroll
            for (int G = 0; G < 4; ++G) acc[G] = MFMA(A1[G][3][0], B3, acc[G]);
            #pragma unroll
            for (int G = 0; G < 4; ++G) acc[G] = MFMA(A1[G][3][1], B3, acc[G]);
            __builtin_amdgcn_s_setprio(0);

            // prefetch h0[t+1] now: latency hides under act+pack+write
            pB0 = LD128(n0P + offL);
            pB1 = LD128(n0P + offH);

            float hv[4];
            #pragma unroll
            for (int j = 0; j < 4; ++j)
                hv[j] = act_fused(acc[0][j], acc[1][j], acc[2][j], acc[3][j], &cst[j]);
            *(uint2*)(wP + woff) = make_uint2(packRne2(hv[0], hv[1]),
                                              packRne2(hv[2], hv[3]));
            if (wrFC) {
                #pragma unroll
                for (int j = 0; j < 4; ++j) fcl[(u0 + j)*17 + rl] = hv[j];
            }
        };

        __syncthreads();                         // i=0 (idle)
        // i=1: prefetch-only — h0[0] lives at parity 1
        pB0 = LD128(h0P1 + offL);
        pB1 = LD128(h0P1 + offH);
        __syncthreads();                         // i=1
        for (int ii = 0; ii < 256; ++ii) {
            // i=2+2ii (p=0): read h1@P0, write@P1, prefetch h0@P0
            body1(h1P0, h1P1, h0P0, false);     __syncthreads();
            // i=3+2ii (p=1): read h1@P1, write@P0, prefetch h0@P1; last (i=513) writes FC
            body1(h1P1, h1P0, h0P1, ii == 255); __syncthreads();
        }
    }

    // ---- FC: out[b] = h1_last[b,:] . W_fc + b_fc ----
    if (tid < 16) {
        float acc = b_fc[0];
        #pragma unroll 16
        for (int u = 0; u < 64; ++u) acc += fcl[u*17 + tid] * W_fc[u];
        out[b0 + tid] = acc;
    }
}

extern "C" void kernel_launch(void* const* d_in, const int* in_sizes, int n_in,
                              void* d_out, int out_size, void* d_ws, size_t ws_size,
                              hipStream_t stream) {
    const float* x     = (const float*)d_in[0];
    const float* W_ih0 = (const float*)d_in[1];
    const float* W_hh0 = (const float*)d_in[2];
    const float* b_ih0 = (const float*)d_in[3];
    const float* b_hh0 = (const float*)d_in[4];
    const float* W_ih1 = (const float*)d_in[5];
    const float* W_hh1 = (const float*)d_in[6];
    const float* b_ih1 = (const float*)d_in[7];
    const float* b_hh1 = (const float*)d_in[8];
    const float* W_fc  = (const float*)d_in[9];
    const float* b_fc  = (const float*)d_in[10];
    float* out = (float*)d_out;

    dim3 grid(4096 / 16), block(NTH);
    hipLaunchKernelGGL(lstm2_mfma, grid, block, 0, stream,
                       x, W_ih0, W_hh0, b_ih0, b_hh0,
                       W_ih1, W_hh1, b_ih1, b_hh1, W_fc, b_fc, out);
}

// Round 11
// 372.160 us; speedup vs baseline: 1.8057x; 1.2701x over previous
//
#include <hip/hip_runtime.h>

#define TSEQ 512
#define NTH  512    // 8 waves: 0-3 layer0, 4-7 layer1 (skew 2); 16 batch/block, 256 blocks = 1/CU
// R11: f16 single-plane for W and h (no hi/lo split anywhere).
// h f16-RNE (2^-12) is 8x MORE precise than R10's bf16 h; W f16 noise is below
// the h-bf16 noise that was already invisible in absmax. MFMA/SIMD/step 52 -> 28.

typedef __attribute__((ext_vector_type(8))) _Float16 half8;
typedef __attribute__((ext_vector_type(4))) float f32x4;
typedef __attribute__((ext_vector_type(4))) unsigned int u32x4;

// pack two f32 into one f16-RNE pair word
__device__ __forceinline__ unsigned packF16x2(float a, float b) {
    _Float16 ha = (_Float16)a, hb = (_Float16)b;
    unsigned short ua = __builtin_bit_cast(unsigned short, ha);
    unsigned short ub = __builtin_bit_cast(unsigned short, hb);
    return (unsigned)ua | ((unsigned)ub << 16);
}
// 8 f32 weights -> f16x8 A-fragment (element e <-> k-offset e)
__device__ __forceinline__ half8 packA16(const float w8[8]) {
    u32x4 W = { packF16x2(w8[0], w8[1]), packF16x2(w8[2], w8[3]),
                packF16x2(w8[4], w8[5]), packF16x2(w8[6], w8[7]) };
    return __builtin_bit_cast(half8, W);
}

#define MFMA(a, b, c) __builtin_amdgcn_mfma_f32_16x16x32_f16((a), (b), (c), 0, 0, 0)
#define LD128H(p) __builtin_bit_cast(half8, *(const u32x4*)(p))

// fused LSTM unit update: 5 exp2 + 3 rcp
__device__ __forceinline__ float act_fused(float ai, float af, float ag, float ao, float* c) {
    const float L2E = 1.44269504088896340736f;
    float ei = __builtin_amdgcn_exp2f(-ai * L2E);
    float ef = __builtin_amdgcn_exp2f(-af * L2E);
    float eg = __builtin_amdgcn_exp2f(2.0f * L2E * ag);
    float eo = __builtin_amdgcn_exp2f(-ao * L2E);
    float sf = __builtin_amdgcn_rcpf(1.0f + ef);
    float ig = (eg - 1.0f) * __builtin_amdgcn_rcpf((1.0f + ei) * (eg + 1.0f));
    float cn = fmaf(*c, sf, ig);
    *c = cn;
    float ec = __builtin_amdgcn_exp2f(2.0f * L2E * cn);
    return (ec - 1.0f) * __builtin_amdgcn_rcpf((1.0f + eo) * (ec + 1.0f));
}

__global__ __launch_bounds__(NTH, 2)
void lstm2_mfma(const float* __restrict__ x,
                const float* __restrict__ W_ih0, const float* __restrict__ W_hh0,
                const float* __restrict__ b_ih0, const float* __restrict__ b_hh0,
                const float* __restrict__ W_ih1, const float* __restrict__ W_hh1,
                const float* __restrict__ b_ih1, const float* __restrict__ b_hh1,
                const float* __restrict__ W_fc,  const float* __restrict__ b_fc,
                float* __restrict__ out)
{
    const int tid  = threadIdx.x;
    const int lane = tid & 63;
    const int wv   = tid >> 6;        // 0-3: layer0, 4-7: layer1
    const int rl   = lane & 15;       // MFMA row/col index = batch col n
    const int g    = lane >> 4;       // k-group 0..3
    const int b0   = blockIdx.x * 16;

    // f16 h planes (2 units/word), depth-2 ping-pong, compile-time bases.
    // h[t] lives at parity (t+1)&1.
    __shared__ unsigned h0P0[512], h0P1[512];
    __shared__ unsigned h1P0[512], h1P1[512];
    __shared__ float fcl[64 * 17];    // padded 16->17

    for (int i2 = tid; i2 < 512; i2 += NTH) {
        h0P0[i2] = 0u; h0P1[i2] = 0u; h1P0[i2] = 0u; h1P1[i2] = 0u;
    }
    __syncthreads();

    // diagonal-swizzle b128 read offsets (loop-invariant)
    const int offL = rl*32 + (((g + rl) & 7) << 2);         // k-half 0
    const int offH = rl*32 + (((4 + g + rl) & 7) << 2);     // k-half 1
    const int q0w  = 8*((wv & 3)) + 2*g;
    const int woff = rl*32 + ((((q0w >> 2) + rl) & 7) << 2) + (q0w & 3);

    if (wv < 4) {
        // ======== LAYER 0: wave w owns u in [16w,16w+16) for all 4 gates ========
        const int w = wv;
        half8 A0[4][2];   // [gate][k-half of W_hh0]
        half8 Ax[4];      // x-term: k0-3 = W_ih0 row (g==0 lanes), else 0
        f32x4 bias4[4];
        #pragma unroll
        for (int G = 0; G < 4; ++G) {
            const int row = 64*G + 16*w + rl;
            #pragma unroll
            for (int s = 0; s < 2; ++s) {
                float w8[8];
                const float* src = W_hh0 + row*64 + s*32 + g*8;
                #pragma unroll
                for (int e = 0; e < 8; ++e) w8[e] = src[e];
                A0[G][s] = packA16(w8);
            }
            {
                u32x4 ax = {0u, 0u, 0u, 0u};
                if (g == 0) {
                    ax.x = packF16x2(W_ih0[row*4+0], W_ih0[row*4+1]);
                    ax.y = packF16x2(W_ih0[row*4+2], W_ih0[row*4+3]);
                }
                Ax[G] = __builtin_bit_cast(half8, ax);
            }
            const int rb = 64*G + 16*w + 4*g;
            bias4[G].x = b_ih0[rb+0] + b_hh0[rb+0];
            bias4[G].y = b_ih0[rb+1] + b_hh0[rb+1];
            bias4[G].z = b_ih0[rb+2] + b_hh0[rb+2];
            bias4[G].w = b_ih0[rb+3] + b_hh0[rb+3];
        }
        float cst[4] = {0.f, 0.f, 0.f, 0.f};

        // x[t] register-prefetched; every lane loads its batch col rl (L1/L2 broadcast)
        f32x4 xcur = *(const f32x4*)(x + ((size_t)(b0 + rl) * TSEQ) * 4);

        auto body0 = [&](const unsigned* rP, unsigned* wP, int i) {
            // h0[t-1] B-frags (f16 single plane)
            half8 B0 = LD128H(rP + offL);
            half8 B1 = LD128H(rP + offH);
            // x B-frag built in-lane from registers (k0-3 = x f16, g==0 lanes)
            u32x4 tx = {0u, 0u, 0u, 0u};
            if (g == 0) {
                tx.x = packF16x2(xcur.x, xcur.y);
                tx.y = packF16x2(xcur.z, xcur.w);
            }
            half8 Bx = __builtin_bit_cast(half8, tx);

            f32x4 acc[4];
            __builtin_amdgcn_s_setprio(1);
            // x-group first: register-only operands, no LDS wait
            #pragma unroll
            for (int G = 0; G < 4; ++G) acc[G] = MFMA(Ax[G], Bx, bias4[G]);
            #pragma unroll
            for (int G = 0; G < 4; ++G) acc[G] = MFMA(A0[G][0], B0, acc[G]);
            #pragma unroll
            for (int G = 0; G < 4; ++G) acc[G] = MFMA(A0[G][1], B1, acc[G]);
            __builtin_amdgcn_s_setprio(0);

            float hv[4];
            #pragma unroll
            for (int j = 0; j < 4; ++j)
                hv[j] = act_fused(acc[0][j], acc[1][j], acc[2][j], acc[3][j], &cst[j]);
            *(uint2*)(wP + woff) = make_uint2(packF16x2(hv[0], hv[1]),
                                              packF16x2(hv[2], hv[3]));

            if (i + 1 < TSEQ)
                xcur = *(const f32x4*)(x + ((size_t)(b0 + rl) * TSEQ + (i + 1)) * 4);
        };

        for (int ii = 0; ii < 256; ++ii) {
            body0(h0P0, h0P1, 2*ii);     __syncthreads();  // i=2ii   (p=0)
            body0(h0P1, h0P0, 2*ii + 1); __syncthreads();  // i=2ii+1 (p=1)
        }
        __syncthreads();   // i=512 slot (L1 tail)
        __syncthreads();   // i=513 slot (L1 tail)
    } else {
        // ======== LAYER 1 (skew 2): iter i computes t=i-2; h0 frags prefetched at i-1 ====
        const int w = wv - 4;
        half8 A1[4][4];   // s=0,1: W_ih1 (vs h0); s=2,3: W_hh1 (vs h1)
        f32x4 bias4[4];
        #pragma unroll
        for (int G = 0; G < 4; ++G) {
            const int row = 64*G + 16*w + rl;
            #pragma unroll
            for (int s = 0; s < 4; ++s) {
                float w8[8];
                const float* src = (s < 2) ? (W_ih1 + row*64 + s*32 + g*8)
                                           : (W_hh1 + row*64 + (s-2)*32 + g*8);
                #pragma unroll
                for (int e = 0; e < 8; ++e) w8[e] = src[e];
                A1[G][s] = packA16(w8);
            }
            const int rb = 64*G + 16*w + 4*g;
            bias4[G].x = b_ih1[rb+0] + b_hh1[rb+0];
            bias4[G].y = b_ih1[rb+1] + b_hh1[rb+1];
            bias4[G].z = b_ih1[rb+2] + b_hh1[rb+2];
            bias4[G].w = b_ih1[rb+3] + b_hh1[rb+3];
        }
        float cst[4] = {0.f, 0.f, 0.f, 0.f};
        const int u0 = 16*w + 4*g;

        half8 pB0 = {}, pB1 = {};   // prefetched h0[t] frags

        auto body1 = [&](const unsigned* r1P,               // h1[t-1] read plane (p)
                         unsigned* wP,                      // h1[t] write plane (p^1)
                         const unsigned* n0P,               // h0 prefetch plane (p)
                         bool wrFC) {
            // h1 reads issue at top; consumed 2 MFMA-groups later (latency hidden)
            half8 B2 = LD128H(r1P + offL);
            half8 B3 = LD128H(r1P + offH);

            f32x4 acc[4];
            __builtin_amdgcn_s_setprio(1);
            // s=0,1 on prefetched h0 frags: start immediately after barrier
            #pragma unroll
            for (int G = 0; G < 4; ++G) acc[G] = MFMA(A1[G][0], pB0, bias4[G]);
            #pragma unroll
            for (int G = 0; G < 4; ++G) acc[G] = MFMA(A1[G][1], pB1, acc[G]);
            // s=2,3 on just-read h1 frags
            #pragma unroll
            for (int G = 0; G < 4; ++G) acc[G] = MFMA(A1[G][2], B2, acc[G]);
            #pragma unroll
            for (int G = 0; G < 4; ++G) acc[G] = MFMA(A1[G][3], B3, acc[G]);
            __builtin_amdgcn_s_setprio(0);

            // prefetch h0[t+1] now: latency hides under act+pack+write
            pB0 = LD128H(n0P + offL);
            pB1 = LD128H(n0P + offH);

            float hv[4];
            #pragma unroll
            for (int j = 0; j < 4; ++j)
                hv[j] = act_fused(acc[0][j], acc[1][j], acc[2][j], acc[3][j], &cst[j]);
            *(uint2*)(wP + woff) = make_uint2(packF16x2(hv[0], hv[1]),
                                              packF16x2(hv[2], hv[3]));
            if (wrFC) {
                #pragma unroll
                for (int j = 0; j < 4; ++j) fcl[(u0 + j)*17 + rl] = hv[j];
            }
        };

        __syncthreads();                         // i=0 (idle)
        // i=1: prefetch-only — h0[0] lives at parity 1
        pB0 = LD128H(h0P1 + offL);
        pB1 = LD128H(h0P1 + offH);
        __syncthreads();                         // i=1
        for (int ii = 0; ii < 256; ++ii) {
            // i=2+2ii (p=0): read h1@P0, write@P1, prefetch h0@P0
            body1(h1P0, h1P1, h0P0, false);     __syncthreads();
            // i=3+2ii (p=1): read h1@P1, write@P0, prefetch h0@P1; last (i=513) writes FC
            body1(h1P1, h1P0, h0P1, ii == 255); __syncthreads();
        }
    }

    // ---- FC: out[b] = h1_last[b,:] . W_fc + b_fc ----
    if (tid < 16) {
        float acc = b_fc[0];
        #pragma unroll 16
        for (int u = 0; u < 64; ++u) acc += fcl[u*17 + tid] * W_fc[u];
        out[b0 + tid] = acc;
    }
}

extern "C" void kernel_launch(void* const* d_in, const int* in_sizes, int n_in,
                              void* d_out, int out_size, void* d_ws, size_t ws_size,
                              hipStream_t stream) {
    const float* x     = (const float*)d_in[0];
    const float* W_ih0 = (const float*)d_in[1];
    const float* W_hh0 = (const float*)d_in[2];
    const float* b_ih0 = (const float*)d_in[3];
    const float* b_hh0 = (const float*)d_in[4];
    const float* W_ih1 = (const float*)d_in[5];
    const float* W_hh1 = (const float*)d_in[6];
    const float* b_ih1 = (const float*)d_in[7];
    const float* b_hh1 = (const float*)d_in[8];
    const float* W_fc  = (const float*)d_in[9];
    const float* b_fc  = (const float*)d_in[10];
    float* out = (float*)d_out;

    dim3 grid(4096 / 16), block(NTH);
    hipLaunchKernelGGL(lstm2_mfma, grid, block, 0, stream,
                       x, W_ih0, W_hh0, b_ih0, b_hh0,
                       W_ih1, W_hh1, b_ih1, b_hh1, W_fc, b_fc, out);
}